// Round 9
// baseline (221.015 us; speedup 1.0000x reference)
//
#include <hip/hip_runtime.h>

#define GRID_N 112
#define O_MAX 48
#define HW_N (GRID_N * GRID_N)   // 12544
#define NT 448                   // 7 wave-private waves; wave w owns row strip w
#define PKB (HW_N / 8)           // 1568 packed bytes per batch

typedef _Float16 half8 __attribute__((ext_vector_type(8)));
typedef float    f32x4 __attribute__((ext_vector_type(4)));
typedef float    f32x2 __attribute__((ext_vector_type(2)));
typedef int      i32x4 __attribute__((ext_vector_type(4)));

constexpr float INV = 1.0f / (2.0f * 5.0f * 5.0f);  // SIGMA = 5.0

// ---- kernel 1: stream road_mask (int32) -> 1 bit/elem in workspace.
// fillBuffer-shaped: grid-stride, dwordx4 reads back-to-back, tiny writes.
// This is the ONLY kernel that touches the 103 MB mask; it does so in the
// pure-streaming regime our captures prove runs at ~6 TB/s.
__global__ __launch_bounds__(256) void pack_mask(
    const int* __restrict__ rm, unsigned char* __restrict__ pk, int total8)
{
    const int idx    = blockIdx.x * 256 + threadIdx.x;
    const int stride = gridDim.x * 256;
    for (int i = idx; i < total8; i += stride) {
        const i32x4* p = (const i32x4*)(rm + (size_t)i * 8);   // 32 B aligned
        i32x4 a = p[0], b = p[1];
        unsigned c = 0;
        c |= (a[0] != 0) ? 1u   : 0u;  c |= (a[1] != 0) ? 2u   : 0u;
        c |= (a[2] != 0) ? 4u   : 0u;  c |= (a[3] != 0) ? 8u   : 0u;
        c |= (b[0] != 0) ? 16u  : 0u;  c |= (b[1] != 0) ? 32u  : 0u;
        c |= (b[2] != 0) ? 64u  : 0u;  c |= (b[3] != 0) ? 128u : 0u;
        pk[i] = (unsigned char)c;
    }
}

// ---- kernel 2: R5's wave-private MFMA structure, but the mask dependency is
// now 28 byte-loads from a 1568 B/block slice of a 3.2 MB array that kernel 1
// just wrote (L2/L3-resident, dirty-in-cache). Front-end load latency
// collapses; the wave is exp/MFMA + a store burst (fillBuffer-with-compute).
__global__ __launch_bounds__(NT) void goalmap_kernel(
    const float* __restrict__ xL, const float* __restrict__ yL,
    const float* __restrict__ obj_list, const int* __restrict__ obj_num,
    const unsigned char* __restrict__ pk, float* __restrict__ out)
{
    const int b    = blockIdx.x;
    const int tid  = threadIdx.x;
    const int lane = tid & 63;
    const int wid  = tid >> 6;                  // 0..6: row strip
    const int m    = lane & 15;
    const int quad = lane >> 4;
    const int h0   = wid * 16 + quad * 4;       // C/D row base

    const int n  = obj_num[b];                  // uniform
    const float xl = xL[b];
    const float yl = yL[b];
    const float* ob = obj_list + (size_t)b * (O_MAX * 2);
    float*       op = out      + (size_t)b * HW_N;

    // ---- (1) packed-mask byte loads (cache-hot, tiny): byte index
    //      (h0+r)*14 + tw*2 + (m>>3); bit position is lane-constant m&7.
    const unsigned char* pb = pk + (size_t)b * PKB;
    const int cb = m >> 3;
    unsigned mb[7][4];
    #pragma unroll
    for (int tw = 0; tw < 7; ++tw)
        #pragma unroll
        for (int r = 0; r < 4; ++r)
            mb[tw][r] = pb[(h0 + r) * 14 + tw * 2 + cb];
    const int bitpos = m & 7;

    // ---- (2) obj-coordinate gathers (L3-resident, small)
    f32x2 oc0[8], oc1[8];
    #pragma unroll
    for (int j = 0; j < 8; ++j) {
        int k = quad * 8 + j;                   // k in [0,32)
        oc0[j] = *(const f32x2*)&ob[k * 2];
        f32x2 z = {0.f, 0.f};
        oc1[j] = (k + 32 < O_MAX) ? *(const f32x2*)&ob[(k + 32) * 2] : z;
    }

    const int ksteps = (n >= 32) ? 2 : 1;       // wave-uniform

    // ---- (3) ex-fragment (carries sign/scale): rows h=wid*16+m
    const float fh = (float)(wid * 16 + m);
    half8 a0, a1;
    #pragma unroll
    for (int j = 0; j < 8; ++j) {
        int k = quad * 8 + j;
        float val = 0.f;
        if (k <= n) {
            float cx = (k < n) ? oc0[j][1] : xl;
            float s  = (k < n) ? -0.5f  : 0.5f;
            float d  = fh - cx;
            val = s * __expf(-d * d * INV);
        }
        a0[j] = (_Float16)val;
    }
    if (ksteps == 2) {
        #pragma unroll
        for (int j = 0; j < 8; ++j) {
            int k = quad * 8 + j + 32;
            float val = 0.f;
            if (k <= n) {
                float cx = (k < n) ? oc1[j][1] : xl;
                float s  = (k < n) ? -0.5f  : 0.5f;
                float d  = fh - cx;
                val = s * __expf(-d * d * INV);
            }
            a1[j] = (_Float16)val;
        }
    }

    // ---- (4) tile sweep: private ey-fragments, MFMA, bit-mask select, store
    #pragma unroll
    for (int tw = 0; tw < 7; ++tw) {
        const float fw = (float)(tw * 16 + m);
        half8 b0;
        #pragma unroll
        for (int j = 0; j < 8; ++j) {
            int k = quad * 8 + j;
            float val = 0.f;
            if (k <= n) {
                float cy = (k < n) ? oc0[j][0] : yl;
                float d  = fw - cy;
                val = __expf(-d * d * INV);
            }
            b0[j] = (_Float16)val;
        }
        f32x4 acc = {0.f, 0.f, 0.f, 0.f};
        acc = __builtin_amdgcn_mfma_f32_16x16x32_f16(a0, b0, acc, 0, 0, 0);
        if (ksteps == 2) {
            half8 b1;
            #pragma unroll
            for (int j = 0; j < 8; ++j) {
                int k = quad * 8 + j + 32;
                float val = 0.f;
                if (k <= n) {
                    float cy = (k < n) ? oc1[j][0] : yl;
                    float d  = fw - cy;
                    val = __expf(-d * d * INV);
                }
                b1[j] = (_Float16)val;
            }
            acc = __builtin_amdgcn_mfma_f32_16x16x32_f16(a1, b1, acc, 0, 0, 0);
        }
        const int w0 = tw * 16 + m;
        #pragma unroll
        for (int r = 0; r < 4; ++r) {
            float v = 0.5f + acc[r];
            v = ((mb[tw][r] >> bitpos) & 1u) ? v : 0.f;
            op[(h0 + r) * GRID_N + w0] = v;
        }
    }
}

extern "C" void kernel_launch(void* const* d_in, const int* in_sizes, int n_in,
                              void* d_out, int out_size, void* d_ws, size_t ws_size,
                              hipStream_t stream) {
    const float* xL        = (const float*)d_in[0];
    const float* yL        = (const float*)d_in[1];
    const float* obj_list  = (const float*)d_in[2];
    const int*   obj_num   = (const int*)d_in[3];
    const int*   road_mask = (const int*)d_in[4];
    float*       out       = (float*)d_out;
    const int B = in_sizes[0];  // 2048

    unsigned char* pk = (unsigned char*)d_ws;   // B*PKB = 3.2 MB
    const int total8 = B * PKB;                 // 3,211,264 packed bytes

    pack_mask<<<2048, 256, 0, stream>>>(road_mask, pk, total8);
    goalmap_kernel<<<B, NT, 0, stream>>>(xL, yL, obj_list, obj_num, pk, out);
}